// Round 2
// baseline (1272.361 us; speedup 1.0000x reference)
//
#include <hip/hip_runtime.h>

typedef unsigned short ushort;
typedef unsigned int uint;

#define D_MODEL 1024
#define NH 16
#define DH 64
#define BATCH 2
#define SEQ 1024
#define MEMLEN 1024
#define TOT 2048

__device__ __forceinline__ float b2f(ushort u) {
  return __uint_as_float(((uint)u) << 16);
}
__device__ __forceinline__ ushort f2b(float f) {
  uint i = __float_as_uint(f);
  uint r = (i + 0x7fffu + ((i >> 16) & 1u)) >> 16;
  return (ushort)r;
}

// ------------------------------------------------- concat + cast to bf16 ----
// xt[b,i,:] = (i < MEM) ? mem[b,i,:] : x[b,i-MEM,:]   (bf16)
// xb[b,s,:] = x[b,s,:]                                 (bf16, for q GEMM)
__global__ __launch_bounds__(256) void concat_cvt_kernel(
    const float* __restrict__ x, const float* __restrict__ mem,
    ushort* __restrict__ xt, ushort* __restrict__ xb) {
  int idx = blockIdx.x * 256 + threadIdx.x;   // 8-elem units
  int row = idx >> 7;                         // 0..4095
  int c8 = (idx & 127) << 3;
  int b = row >> 11;
  int i = row & 2047;
  const float* src = (i < MEMLEN) ? &mem[((b << 10) + i) * D_MODEL]
                                  : &x[((b << 10) + (i - MEMLEN)) * D_MODEL];
  float4 f0 = *(const float4*)(&src[c8]);
  float4 f1 = *(const float4*)(&src[c8 + 4]);
  ushort u[8] = {f2b(f0.x), f2b(f0.y), f2b(f0.z), f2b(f0.w),
                 f2b(f1.x), f2b(f1.y), f2b(f1.z), f2b(f1.w)};
  *(uint4*)(&xt[row * D_MODEL + c8]) = *(const uint4*)u;
  if (i >= MEMLEN)
    *(uint4*)(&xb[((b << 10) + (i - MEMLEN)) * D_MODEL + c8]) = *(const uint4*)u;
}

// --------------------------------------------------- fp32 -> bf16 cast ------
__global__ __launch_bounds__(256) void cvt_kernel(const float* __restrict__ in,
                                                  ushort* __restrict__ out) {
  int idx = blockIdx.x * 256 + threadIdx.x;
  int base = idx << 3;
  float4 f0 = *(const float4*)(&in[base]);
  float4 f1 = *(const float4*)(&in[base + 4]);
  ushort u[8] = {f2b(f0.x), f2b(f0.y), f2b(f0.z), f2b(f0.w),
                 f2b(f1.x), f2b(f1.y), f2b(f1.z), f2b(f1.w)};
  *(uint4*)(&out[base]) = *(const uint4*)u;
}

// ------------------------------------------- transpose + cast to bf16 -------
// WT[n][k] = bf16(W[k][n]), 1024x1024
__global__ __launch_bounds__(256) void transpose_cvt_kernel(
    const float* __restrict__ W, ushort* __restrict__ WT) {
  __shared__ ushort tle[32][33];
  const int bx = blockIdx.x * 32, by = blockIdx.y * 32;
  const int tx = threadIdx.x & 31, ty = threadIdx.x >> 5;   // ty 0..7
#pragma unroll
  for (int j = 0; j < 32; j += 8)
    tle[ty + j][tx] = f2b(W[(by + ty + j) * 1024 + bx + tx]);
  __syncthreads();
#pragma unroll
  for (int j = 0; j < 32; j += 8)
    WT[(bx + ty + j) * 1024 + by + tx] = tle[tx][ty + j];
}

// ------------------------------------------------------------------ GEMM ----
// C[M x N] = A[M x K] @ BT[N x K]^T + bias, A/BT bf16, f32 accumulate.
// 64x64 tile, BK=32, 4 waves. MFMA 16x16x32 bf16. F32OUT: fp32 C else bf16 C.
typedef __attribute__((ext_vector_type(8))) short short8;
typedef __attribute__((ext_vector_type(4))) float float4v;

template <bool F32OUT>
__global__ __launch_bounds__(256) void gemm_bt_kernel(
    const ushort* __restrict__ A, const ushort* __restrict__ BT,
    const float* __restrict__ bias, void* __restrict__ Cout,
    int M, int N, int K) {
  __shared__ ushort As[64][40];   // stride 40 bf16: 16B-aligned frags
  __shared__ ushort Bs[64][40];
  const int m0 = blockIdx.x * 64;
  const int n0 = blockIdx.y * 64;
  const int tid = threadIdx.x;
  const int wave = tid >> 6;
  const int lane = tid & 63;
  const int m15 = lane & 15;
  const int q4 = lane >> 4;        // 0..3
  const int sr = tid >> 2;         // staging row 0..63
  const int sc = (tid & 3) * 8;    // staging col 0,8,16,24

  float4v acc0 = {0.f, 0.f, 0.f, 0.f};
  float4v acc1 = acc0, acc2 = acc0, acc3 = acc0;

  for (int kbase = 0; kbase < K; kbase += 32) {
    __syncthreads();
    *(uint4*)(&As[sr][sc]) = *(const uint4*)(&A[(m0 + sr) * K + kbase + sc]);
    *(uint4*)(&Bs[sr][sc]) = *(const uint4*)(&BT[(n0 + sr) * K + kbase + sc]);
    __syncthreads();
    short8 af = *(const short8*)(&As[wave * 16 + m15][q4 * 8]);
    short8 b0 = *(const short8*)(&Bs[0 + m15][q4 * 8]);
    short8 b1 = *(const short8*)(&Bs[16 + m15][q4 * 8]);
    short8 b2 = *(const short8*)(&Bs[32 + m15][q4 * 8]);
    short8 b3 = *(const short8*)(&Bs[48 + m15][q4 * 8]);
    acc0 = __builtin_amdgcn_mfma_f32_16x16x32_bf16(af, b0, acc0, 0, 0, 0);
    acc1 = __builtin_amdgcn_mfma_f32_16x16x32_bf16(af, b1, acc1, 0, 0, 0);
    acc2 = __builtin_amdgcn_mfma_f32_16x16x32_bf16(af, b2, acc2, 0, 0, 0);
    acc3 = __builtin_amdgcn_mfma_f32_16x16x32_bf16(af, b3, acc3, 0, 0, 0);
  }
  // C/D layout: col = lane&15, row = q4*4 + i  [m89/m91 verified]
  const int crow0 = m0 + wave * 16 + q4 * 4;
#pragma unroll
  for (int j = 0; j < 4; ++j) {
    float4v a = (j == 0) ? acc0 : (j == 1) ? acc1 : (j == 2) ? acc2 : acc3;
    int col = n0 + j * 16 + m15;
    float bval = bias[col];
#pragma unroll
    for (int i = 0; i < 4; ++i) {
      float v = a[i] + bval;
      if (F32OUT)
        ((float*)Cout)[(crow0 + i) * N + col] = v;
      else
        ((ushort*)Cout)[(crow0 + i) * N + col] = f2b(v);
    }
  }
}

// ------------------------------------------------------- fused attention ----
// Per block: 16 query rows of one (b,h). Online (no-max) softmax over t-chunks
// of 128. Rel-shift: u = t-s+1023; u<2048 -> q[s].Q[u]; u==2048 -> 0;
// u>2048 -> q[s+1].Q[u-2049].
#define ST 16
#define TC 128
#define QPAD 76          // bf16 row stride: 152B (8B aligned)
#define WROWS (TC + 16)  // 144 staged window rows

__global__ __launch_bounds__(256, 2) void attn_kernel(
    const ushort* __restrict__ qb, const ushort* __restrict__ kb,
    const ushort* __restrict__ vb, const ushort* __restrict__ Qr,
    const float* __restrict__ mask, ushort* __restrict__ attn) {
  __shared__ float qs[ST + 1][DH];      // q rows s0..s0+16 (f32)
  __shared__ ushort Qm[WROWS][QPAD];    // main window: u = umin + r
  __shared__ ushort Qw[WROWS][QPAD];    // wrap window: j = umin - 2049 + r
  __shared__ float Pc[ST][TC + 1];      // exp(scores) chunk
  __shared__ float red[ST][17];
  __shared__ float lsum[ST];

  const int s0 = blockIdx.x * ST;
  const int h = blockIdx.y;
  const int b = blockIdx.z;
  const int tid = threadIdx.x;

  for (int idx = tid; idx < (ST + 1) * DH; idx += 256) {
    int rr = idx >> 6, d = idx & 63;
    int srow = s0 + rr;
    qs[rr][d] =
        (srow < SEQ) ? b2f(qb[((b << 10) + srow) * D_MODEL + (h << 6) + d]) : 0.f;
  }
  if (tid < ST) lsum[tid] = 0.f;

  const int tl = tid & (TC - 1);      // 0..127: t within chunk
  const int sbase = (tid >> 7) * 8;   // thread half -> si 0..7 or 8..15
  const int dl = tid & 63;            // AV: d
  const int sg = tid >> 6;            // AV: wave owns rows sg, sg+4, sg+8, sg+12
  float o0 = 0.f, o1 = 0.f, o2 = 0.f, o3 = 0.f;

  for (int t0 = 0; t0 < TOT; t0 += TC) {
    const int umin = t0 - s0 + (SEQ - 1) - (ST - 1);  // t0 - s0 + 1008
    const int jmin = umin - (TOT + 1);
    __syncthreads();
    // stage Q windows (uint2 = 4 bf16 per unit, 16 units/row)
    for (int idx = tid; idx < WROWS * 16; idx += 256) {
      int rr = idx >> 4, c4 = (idx & 15) << 2;
      int u = umin + rr;
      uint2 va = make_uint2(0u, 0u);
      if (u >= 0 && u < TOT) va = *(const uint2*)(&Qr[u * D_MODEL + (h << 6) + c4]);
      *(uint2*)(&Qm[rr][c4]) = va;
      int j = jmin + rr;
      uint2 vw = make_uint2(0u, 0u);
      if (j >= 0 && j < TOT) vw = *(const uint2*)(&Qr[j * D_MODEL + (h << 6) + c4]);
      *(uint2*)(&Qw[rr][c4]) = vw;
    }
    __syncthreads();

    const int t = t0 + tl;
    // k row -> registers
    uint kw[32];
    const ushort* kp = &kb[((b << 11) + t) * D_MODEL + (h << 6)];
#pragma unroll
    for (int i = 0; i < 8; ++i)
      *(uint4*)(&kw[i * 4]) = *(const uint4*)(&kp[i * 8]);
    float kf[64];
#pragma unroll
    for (int i = 0; i < 32; ++i) {
      kf[2 * i] = b2f((ushort)(kw[i] & 0xffffu));
      kf[2 * i + 1] = b2f((ushort)(kw[i] >> 16));
    }

    for (int ii = 0; ii < 8; ++ii) {
      const int si = sbase + ii;
      const int s = s0 + si;
      float qr[64];
#pragma unroll
      for (int d = 0; d < 64; ++d) qr[d] = qs[si][d];
      float a0 = 0, a1 = 0, a2 = 0, a3 = 0;
#pragma unroll
      for (int d = 0; d < 64; d += 4) {
        a0 += kf[d] * qr[d];
        a1 += kf[d + 1] * qr[d + 1];
        a2 += kf[d + 2] * qr[d + 2];
        a3 += kf[d + 3] * qr[d + 3];
      }
      float accA = (a0 + a1) + (a2 + a3);
      const int u = t - s + (SEQ - 1);
      float accB = 0.f;
      if (u < TOT) {
        const int rl = u - umin;
        const ushort* Qrow = &Qm[rl][0];
        float c0 = 0, c1 = 0, c2 = 0, c3 = 0;
#pragma unroll
        for (int d = 0; d < 64; d += 4) {
          uint2 w2 = *(const uint2*)(&Qrow[d]);
          c0 += b2f((ushort)(w2.x & 0xffffu)) * qr[d];
          c1 += b2f((ushort)(w2.x >> 16)) * qr[d + 1];
          c2 += b2f((ushort)(w2.y & 0xffffu)) * qr[d + 2];
          c3 += b2f((ushort)(w2.y >> 16)) * qr[d + 3];
        }
        accB = (c0 + c1) + (c2 + c3);
      } else if (u > TOT) {
        const int rl = u - umin;  // == (u-2049) - jmin
        const ushort* Qrow = &Qw[rl][0];
        float c0 = 0, c1 = 0, c2 = 0, c3 = 0;
#pragma unroll
        for (int d = 0; d < 64; d += 4) {
          uint2 w2 = *(const uint2*)(&Qrow[d]);
          c0 += b2f((ushort)(w2.x & 0xffffu)) * qs[si + 1][d];
          c1 += b2f((ushort)(w2.x >> 16)) * qs[si + 1][d + 1];
          c2 += b2f((ushort)(w2.y & 0xffffu)) * qs[si + 1][d + 2];
          c3 += b2f((ushort)(w2.y >> 16)) * qs[si + 1][d + 3];
        }
        accB = (c0 + c1) + (c2 + c3);
      }
      float sc = (accA + accB) * 0.125f + mask[s * TOT + t] * -1e9f;
      Pc[si][tl] = __expf(sc);
    }
    __syncthreads();

    // partial row sums of this chunk
    {
      int g = tid >> 4, e = tid & 15;
      float p = 0.f;
#pragma unroll
      for (int mm = 0; mm < TC / 16; ++mm) p += Pc[g][e + mm * 16];
      red[g][e] = p;
    }
    // P.V accumulation; v read coalesced from global (L1/L2-hot)
    const ushort* vp = &vb[((b << 11) + t0) * D_MODEL + (h << 6) + dl];
#pragma unroll 8
    for (int tt = 0; tt < TC; ++tt) {
      float vf = b2f(vp[tt * D_MODEL]);
      o0 += Pc[sg][tt] * vf;
      o1 += Pc[sg + 4][tt] * vf;
      o2 += Pc[sg + 8][tt] * vf;
      o3 += Pc[sg + 12][tt] * vf;
    }
    __syncthreads();
    if (tid < ST) {
      float ss = 0.f;
#pragma unroll
      for (int e = 0; e < 16; ++e) ss += red[tid][e];
      lsum[tid] += ss;
    }
  }
  __syncthreads();
  const int ob = ((b << 10) + s0) * D_MODEL + (h << 6) + dl;
  attn[ob + sg * D_MODEL] = f2b(o0 / lsum[sg]);
  attn[ob + (sg + 4) * D_MODEL] = f2b(o1 / lsum[sg + 4]);
  attn[ob + (sg + 8) * D_MODEL] = f2b(o2 / lsum[sg + 8]);
  attn[ob + (sg + 12) * D_MODEL] = f2b(o3 / lsum[sg + 12]);
}

// ---------------------------------------------------------------- launch ----
extern "C" void kernel_launch(void* const* d_in, const int* in_sizes, int n_in,
                              void* d_out, int out_size, void* d_ws,
                              size_t ws_size, hipStream_t stream) {
  const float* x = (const float*)d_in[0];
  const float* mem = (const float*)d_in[1];
  const float* mask = (const float*)d_in[2];
  const float* rel = (const float*)d_in[3];
  const float* Wq = (const float*)d_in[4];
  const float* bq = (const float*)d_in[5];
  const float* Wke = (const float*)d_in[6];
  const float* bke = (const float*)d_in[7];
  const float* Wkr = (const float*)d_in[8];
  const float* bkr = (const float*)d_in[9];
  const float* Wv = (const float*)d_in[10];
  const float* bv = (const float*)d_in[11];
  const float* Wo = (const float*)d_in[12];
  const float* bo = (const float*)d_in[13];
  float* out = (float*)d_out;

  char* ws = (char*)d_ws;
  ushort* xt = (ushort*)ws;                         // 4096x1024 bf16 (8 MB)
  ushort* xb = xt + 4096 * 1024;                    // 2048x1024 bf16 (4 MB)
  ushort* relb = xb + 2048 * 1024;                  // 2048x1024 bf16 (4 MB)
  ushort* WqT = relb + 2048 * 1024;                 // 5 x 1024x1024 bf16 (10 MB)
  ushort* WkeT = WqT + 1024 * 1024;
  ushort* WkrT = WkeT + 1024 * 1024;
  ushort* WvT = WkrT + 1024 * 1024;
  ushort* WoT = WvT + 1024 * 1024;
  ushort* qbuf = WoT + 1024 * 1024;                 // 2048x1024 (4 MB)
  ushort* kbuf = qbuf + 2048 * 1024;                // 4096x1024 (8 MB)
  ushort* vbuf = kbuf + 4096 * 1024;                // 4096x1024 (8 MB)
  ushort* Qrb = vbuf + 4096 * 1024;                 // 2048x1024 (4 MB)
  ushort* attn = Qrb + 2048 * 1024;                 // 2048x1024 (4 MB)
  // total ws use: ~54 MB

  concat_cvt_kernel<<<2048, 256, 0, stream>>>(x, mem, xt, xb);
  cvt_kernel<<<1024, 256, 0, stream>>>(rel, relb);
  transpose_cvt_kernel<<<dim3(32, 32), 256, 0, stream>>>(Wq, WqT);
  transpose_cvt_kernel<<<dim3(32, 32), 256, 0, stream>>>(Wke, WkeT);
  transpose_cvt_kernel<<<dim3(32, 32), 256, 0, stream>>>(Wkr, WkrT);
  transpose_cvt_kernel<<<dim3(32, 32), 256, 0, stream>>>(Wv, WvT);
  transpose_cvt_kernel<<<dim3(32, 32), 256, 0, stream>>>(Wo, WoT);

  gemm_bt_kernel<false><<<dim3(32, 16), 256, 0, stream>>>(xb, WqT, bq, qbuf, 2048, 1024, 1024);
  gemm_bt_kernel<false><<<dim3(64, 16), 256, 0, stream>>>(xt, WkeT, bke, kbuf, 4096, 1024, 1024);
  gemm_bt_kernel<false><<<dim3(64, 16), 256, 0, stream>>>(xt, WvT, bv, vbuf, 4096, 1024, 1024);
  gemm_bt_kernel<false><<<dim3(32, 16), 256, 0, stream>>>(relb, WkrT, bkr, Qrb, 2048, 1024, 1024);

  attn_kernel<<<dim3(SEQ / ST, NH, BATCH), 256, 0, stream>>>(qbuf, kbuf, vbuf,
                                                             Qrb, mask, attn);

  gemm_bt_kernel<true><<<dim3(32, 16), 256, 0, stream>>>(attn, WoT, bo, out, 2048, 1024, 1024);
}

// Round 3
// 495.360 us; speedup vs baseline: 2.5686x; 2.5686x over previous
//
#include <hip/hip_runtime.h>

typedef unsigned short ushort;
typedef unsigned int uint;

#define D_MODEL 1024
#define NH 16
#define DH 64
#define BATCH 2
#define SEQ 1024
#define MEMLEN 1024
#define TOT 2048

__device__ __forceinline__ float b2f(ushort u) {
  return __uint_as_float(((uint)u) << 16);
}
__device__ __forceinline__ ushort f2b(float f) {
  uint i = __float_as_uint(f);
  uint r = (i + 0x7fffu + ((i >> 16) & 1u)) >> 16;
  return (ushort)r;
}

// ------------------------------------------------- concat + cast to bf16 ----
__global__ __launch_bounds__(256) void concat_cvt_kernel(
    const float* __restrict__ x, const float* __restrict__ mem,
    ushort* __restrict__ xt, ushort* __restrict__ xb) {
  int idx = blockIdx.x * 256 + threadIdx.x;   // 8-elem units
  int row = idx >> 7;                         // 0..4095
  int c8 = (idx & 127) << 3;
  int b = row >> 11;
  int i = row & 2047;
  const float* src = (i < MEMLEN) ? &mem[((b << 10) + i) * D_MODEL]
                                  : &x[((b << 10) + (i - MEMLEN)) * D_MODEL];
  float4 f0 = *(const float4*)(&src[c8]);
  float4 f1 = *(const float4*)(&src[c8 + 4]);
  ushort u[8] = {f2b(f0.x), f2b(f0.y), f2b(f0.z), f2b(f0.w),
                 f2b(f1.x), f2b(f1.y), f2b(f1.z), f2b(f1.w)};
  *(uint4*)(&xt[row * D_MODEL + c8]) = *(const uint4*)u;
  if (i >= MEMLEN)
    *(uint4*)(&xb[((b << 10) + (i - MEMLEN)) * D_MODEL + c8]) = *(const uint4*)u;
}

// --------------------------------------------------- fp32 -> bf16 cast ------
__global__ __launch_bounds__(256) void cvt_kernel(const float* __restrict__ in,
                                                  ushort* __restrict__ out) {
  int idx = blockIdx.x * 256 + threadIdx.x;
  int base = idx << 3;
  float4 f0 = *(const float4*)(&in[base]);
  float4 f1 = *(const float4*)(&in[base + 4]);
  ushort u[8] = {f2b(f0.x), f2b(f0.y), f2b(f0.z), f2b(f0.w),
                 f2b(f1.x), f2b(f1.y), f2b(f1.z), f2b(f1.w)};
  *(uint4*)(&out[base]) = *(const uint4*)u;
}

// ------------------------------------------- transpose + cast to bf16 -------
__global__ __launch_bounds__(256) void transpose_cvt_kernel(
    const float* __restrict__ W, ushort* __restrict__ WT) {
  __shared__ ushort tle[32][33];
  const int bx = blockIdx.x * 32, by = blockIdx.y * 32;
  const int tx = threadIdx.x & 31, ty = threadIdx.x >> 5;
#pragma unroll
  for (int j = 0; j < 32; j += 8)
    tle[ty + j][tx] = f2b(W[(by + ty + j) * 1024 + bx + tx]);
  __syncthreads();
#pragma unroll
  for (int j = 0; j < 32; j += 8)
    WT[(bx + ty + j) * 1024 + by + tx] = tle[tx][ty + j];
}

// ------------------------------------------------------------------ GEMM ----
typedef __attribute__((ext_vector_type(8))) short short8;
typedef __attribute__((ext_vector_type(4))) float float4v;

template <bool F32OUT>
__global__ __launch_bounds__(256) void gemm_bt_kernel(
    const ushort* __restrict__ A, const ushort* __restrict__ BT,
    const float* __restrict__ bias, void* __restrict__ Cout,
    int M, int N, int K) {
  __shared__ ushort As[64][40];
  __shared__ ushort Bs[64][40];
  const int m0 = blockIdx.x * 64;
  const int n0 = blockIdx.y * 64;
  const int tid = threadIdx.x;
  const int wave = tid >> 6;
  const int lane = tid & 63;
  const int m15 = lane & 15;
  const int q4 = lane >> 4;
  const int sr = tid >> 2;
  const int sc = (tid & 3) * 8;

  float4v acc0 = {0.f, 0.f, 0.f, 0.f};
  float4v acc1 = acc0, acc2 = acc0, acc3 = acc0;

  for (int kbase = 0; kbase < K; kbase += 32) {
    __syncthreads();
    *(uint4*)(&As[sr][sc]) = *(const uint4*)(&A[(m0 + sr) * K + kbase + sc]);
    *(uint4*)(&Bs[sr][sc]) = *(const uint4*)(&BT[(n0 + sr) * K + kbase + sc]);
    __syncthreads();
    short8 af = *(const short8*)(&As[wave * 16 + m15][q4 * 8]);
    short8 b0 = *(const short8*)(&Bs[0 + m15][q4 * 8]);
    short8 b1 = *(const short8*)(&Bs[16 + m15][q4 * 8]);
    short8 b2 = *(const short8*)(&Bs[32 + m15][q4 * 8]);
    short8 b3 = *(const short8*)(&Bs[48 + m15][q4 * 8]);
    acc0 = __builtin_amdgcn_mfma_f32_16x16x32_bf16(af, b0, acc0, 0, 0, 0);
    acc1 = __builtin_amdgcn_mfma_f32_16x16x32_bf16(af, b1, acc1, 0, 0, 0);
    acc2 = __builtin_amdgcn_mfma_f32_16x16x32_bf16(af, b2, acc2, 0, 0, 0);
    acc3 = __builtin_amdgcn_mfma_f32_16x16x32_bf16(af, b3, acc3, 0, 0, 0);
  }
  const int crow0 = m0 + wave * 16 + q4 * 4;
#pragma unroll
  for (int j = 0; j < 4; ++j) {
    float4v a = (j == 0) ? acc0 : (j == 1) ? acc1 : (j == 2) ? acc2 : acc3;
    int col = n0 + j * 16 + m15;
    float bval = bias[col];
#pragma unroll
    for (int i = 0; i < 4; ++i) {
      float v = a[i] + bval;
      if (F32OUT)
        ((float*)Cout)[(crow0 + i) * N + col] = v;
      else
        ((ushort*)Cout)[(crow0 + i) * N + col] = f2b(v);
    }
  }
}

// ------------------------------------------- fused MFMA flash attention -----
// Block: 32 q-rows of one (b,h), 4 waves, t-chunks of 64.
// u = t-s+1023. Main: q[s].Qrel[u] (u<=2047); wrap: q[s+1].Qrel[u-2049]
// (u>=2049); u==2048 -> 0 (OOB window rows staged as zeros).
// Window m = u - umin = tl - sl + 31 in [0,94]; t_local = m + sl - 31.
#define ST 32
#define TC 64
#define LQ 72     // ushort stride (144 B rows: 16B-aligned, ~2-way banks)
#define BW 96     // staged window rows

__global__ __launch_bounds__(256, 2) void attn_mfma_kernel(
    const ushort* __restrict__ qb, const ushort* __restrict__ kb,
    const ushort* __restrict__ vb, const ushort* __restrict__ Qr,
    const float* __restrict__ mask, ushort* __restrict__ attn) {
  __shared__ ushort qA[ST + 1][LQ];   // q rows s0..s0+32
  __shared__ ushort Kc[TC][LQ];       // K chunk [t][dh]
  __shared__ ushort Vc[TC][LQ];       // V chunk [t][dh]
  __shared__ ushort Wm[BW][LQ];       // Qrel main window
  __shared__ ushort Ww[BW][LQ];       // Qrel wrap window
  __shared__ float Btile[ST][66];     // B-term (s x t) fp32
  __shared__ ushort Pt[ST][LQ];       // exp(scores) bf16
  __shared__ float red[ST][8];
  __shared__ float lsum[ST];

  const int s0 = blockIdx.x * ST;
  const int h = blockIdx.y;
  const int b = blockIdx.z;
  const int tid = threadIdx.x;
  const int w = tid >> 6;
  const int lane = tid & 63;
  const int m15 = lane & 15;
  const int q4 = lane >> 4;

  // stage qA (33 rows; row 32 OOB at s0=992 -> zero; only multiplies zeros)
  for (int idx = tid; idx < (ST + 1) * 8; idx += 256) {
    int r = idx >> 3, c8 = (idx & 7) * 8;
    int srow = s0 + r;
    uint4 v = make_uint4(0u, 0u, 0u, 0u);
    if (srow < SEQ)
      v = *(const uint4*)(&qb[((b << 10) + srow) * D_MODEL + (h << 6) + c8]);
    *(uint4*)(&qA[r][c8]) = v;
  }
  if (tid < ST) lsum[tid] = 0.f;

  float4v oacc0 = {0.f, 0.f, 0.f, 0.f};   // PV acc rows 0..15 (nt=w)
  float4v oacc1 = oacc0;                  // PV acc rows 16..31

  for (int t0 = 0; t0 < TOT; t0 += TC) {
    const int umin = t0 - s0 + (SEQ - 1) - (ST - 1);  // t0-s0+992, >=0
    const bool mainN = (umin <= TOT - 1);
    const bool wrapN = (umin + (BW - 2) >= TOT + 1);
    __syncthreads();  // (a): prev chunk's LDS reads done

    if (t0 > 0 && tid < ST) {
      float ss = 0.f;
#pragma unroll
      for (int j = 0; j < 8; ++j) ss += red[tid][j];
      lsum[tid] += ss;
    }
    // stage K and V chunks (64 rows x 64 bf16 each)
    for (int idx = tid; idx < TC * 8 * 2; idx += 256) {
      int unit = idx & (TC * 8 - 1);
      int r = unit >> 3, c8 = (unit & 7) * 8;
      if (idx < TC * 8) {
        *(uint4*)(&Kc[r][c8]) =
            *(const uint4*)(&kb[((b << 11) + t0 + r) * D_MODEL + (h << 6) + c8]);
      } else {
        *(uint4*)(&Vc[r][c8]) =
            *(const uint4*)(&vb[((b << 11) + t0 + r) * D_MODEL + (h << 6) + c8]);
      }
    }
    if (mainN) {
      for (int idx = tid; idx < BW * 8; idx += 256) {
        int r = idx >> 3, c8 = (idx & 7) * 8;
        int u = umin + r;
        uint4 v = make_uint4(0u, 0u, 0u, 0u);
        if (u < TOT) v = *(const uint4*)(&Qr[u * D_MODEL + (h << 6) + c8]);
        *(uint4*)(&Wm[r][c8]) = v;
      }
    }
    if (wrapN) {
      for (int idx = tid; idx < BW * 8; idx += 256) {
        int r = idx >> 3, c8 = (idx & 7) * 8;
        int j = umin - (TOT + 1) + r;
        uint4 v = make_uint4(0u, 0u, 0u, 0u);
        if (j >= 0) v = *(const uint4*)(&Qr[j * D_MODEL + (h << 6) + c8]);
        *(uint4*)(&Ww[r][c8]) = v;
      }
    }
    for (int idx = tid; idx < ST * 66; idx += 256) ((float*)Btile)[idx] = 0.f;
    __syncthreads();  // (b): staging + zero done

    // ---- B-term GEMMs (32 x 96), diagonal scatter into Btile ----
    if (mainN) {
#pragma unroll
      for (int j3 = 0; j3 < 3; ++j3) {
        int idx3 = w * 3 + j3, mh = idx3 & 1, nt = idx3 >> 1;
        float4v c = {0.f, 0.f, 0.f, 0.f};
#pragma unroll
        for (int ks = 0; ks < 2; ++ks) {
          short8 af = *(const short8*)(&qA[mh * 16 + m15][ks * 32 + q4 * 8]);
          short8 bf = *(const short8*)(&Wm[nt * 16 + m15][ks * 32 + q4 * 8]);
          c = __builtin_amdgcn_mfma_f32_16x16x32_bf16(af, bf, c, 0, 0, 0);
        }
        int slb = mh * 16 + q4 * 4, m = nt * 16 + m15;
#pragma unroll
        for (int i = 0; i < 4; ++i) {
          int tl = m + slb + i - (ST - 1);
          if ((unsigned)tl < TC) Btile[slb + i][tl] += c[i];
        }
      }
    }
    if (wrapN) {
#pragma unroll
      for (int j3 = 0; j3 < 3; ++j3) {
        int idx3 = w * 3 + j3, mh = idx3 & 1, nt = idx3 >> 1;
        float4v c = {0.f, 0.f, 0.f, 0.f};
#pragma unroll
        for (int ks = 0; ks < 2; ++ks) {
          short8 af = *(const short8*)(&qA[mh * 16 + m15 + 1][ks * 32 + q4 * 8]);
          short8 bf = *(const short8*)(&Ww[nt * 16 + m15][ks * 32 + q4 * 8]);
          c = __builtin_amdgcn_mfma_f32_16x16x32_bf16(af, bf, c, 0, 0, 0);
        }
        int slb = mh * 16 + q4 * 4, m = nt * 16 + m15;
#pragma unroll
        for (int i = 0; i < 4; ++i) {
          int tl = m + slb + i - (ST - 1);
          if ((unsigned)tl < TC) Btile[slb + i][tl] += c[i];
        }
      }
    }
    // ---- A-term GEMM: wave w owns t-cols w*16..w*16+15 ----
    float4v aA0 = {0.f, 0.f, 0.f, 0.f};
    float4v aA1 = aA0;
#pragma unroll
    for (int ks = 0; ks < 2; ++ks) {
      short8 bf = *(const short8*)(&Kc[w * 16 + m15][ks * 32 + q4 * 8]);
      short8 a0 = *(const short8*)(&qA[m15][ks * 32 + q4 * 8]);
      short8 a1 = *(const short8*)(&qA[16 + m15][ks * 32 + q4 * 8]);
      aA0 = __builtin_amdgcn_mfma_f32_16x16x32_bf16(a0, bf, aA0, 0, 0, 0);
      aA1 = __builtin_amdgcn_mfma_f32_16x16x32_bf16(a1, bf, aA1, 0, 0, 0);
    }
    __syncthreads();  // (c): Btile scatter complete

    // ---- scores -> exp -> Pt ----
    {
      int tl = w * 16 + m15;
      int t = t0 + tl;
#pragma unroll
      for (int mh = 0; mh < 2; ++mh) {
        float4v aa = mh ? aA1 : aA0;
        int slb = mh * 16 + q4 * 4;
#pragma unroll
        for (int i = 0; i < 4; ++i) {
          int sl = slb + i;
          float val = (aa[i] + Btile[sl][tl]) * 0.125f +
                      mask[(s0 + sl) * TOT + t] * -1e9f;
          Pt[sl][tl] = f2b(__expf(val));
        }
      }
    }
    __syncthreads();  // (d): Pt complete

    // partial row sums (deterministic)
    {
      int row = tid >> 3, cb = (tid & 7) * 8;
      float ss = 0.f;
#pragma unroll
      for (int j = 0; j < 8; ++j) ss += b2f(Pt[row][cb + j]);
      red[row][tid & 7] = ss;
    }
    // ---- PV MFMA: wave w owns dh-cols w*16..w*16+15 ----
#pragma unroll
    for (int ks = 0; ks < 2; ++ks) {
      short8 vf;
#pragma unroll
      for (int j = 0; j < 8; ++j)
        vf[j] = (short)Vc[ks * 32 + q4 * 8 + j][w * 16 + m15];
      short8 p0 = *(const short8*)(&Pt[m15][ks * 32 + q4 * 8]);
      short8 p1 = *(const short8*)(&Pt[16 + m15][ks * 32 + q4 * 8]);
      oacc0 = __builtin_amdgcn_mfma_f32_16x16x32_bf16(p0, vf, oacc0, 0, 0, 0);
      oacc1 = __builtin_amdgcn_mfma_f32_16x16x32_bf16(p1, vf, oacc1, 0, 0, 0);
    }
  }
  __syncthreads();
  if (tid < ST) {
    float ss = 0.f;
#pragma unroll
    for (int j = 0; j < 8; ++j) ss += red[tid][j];
    lsum[tid] += ss;
  }
  __syncthreads();
#pragma unroll
  for (int mh = 0; mh < 2; ++mh) {
    float4v acc = mh ? oacc1 : oacc0;
#pragma unroll
    for (int i = 0; i < 4; ++i) {
      int sl = mh * 16 + q4 * 4 + i;
      attn[((b << 10) + s0 + sl) * D_MODEL + (h << 6) + w * 16 + m15] =
          f2b(acc[i] / lsum[sl]);
    }
  }
}

// ---------------------------------------------------------------- launch ----
extern "C" void kernel_launch(void* const* d_in, const int* in_sizes, int n_in,
                              void* d_out, int out_size, void* d_ws,
                              size_t ws_size, hipStream_t stream) {
  const float* x = (const float*)d_in[0];
  const float* mem = (const float*)d_in[1];
  const float* mask = (const float*)d_in[2];
  const float* rel = (const float*)d_in[3];
  const float* Wq = (const float*)d_in[4];
  const float* bq = (const float*)d_in[5];
  const float* Wke = (const float*)d_in[6];
  const float* bke = (const float*)d_in[7];
  const float* Wkr = (const float*)d_in[8];
  const float* bkr = (const float*)d_in[9];
  const float* Wv = (const float*)d_in[10];
  const float* bv = (const float*)d_in[11];
  const float* Wo = (const float*)d_in[12];
  const float* bo = (const float*)d_in[13];
  float* out = (float*)d_out;

  char* ws = (char*)d_ws;
  ushort* xt = (ushort*)ws;                         // 4096x1024 bf16
  ushort* xb = xt + 4096 * 1024;                    // 2048x1024
  ushort* relb = xb + 2048 * 1024;                  // 2048x1024
  ushort* WqT = relb + 2048 * 1024;                 // 5 x 1024x1024
  ushort* WkeT = WqT + 1024 * 1024;
  ushort* WkrT = WkeT + 1024 * 1024;
  ushort* WvT = WkrT + 1024 * 1024;
  ushort* WoT = WvT + 1024 * 1024;
  ushort* qbuf = WoT + 1024 * 1024;                 // 2048x1024
  ushort* kbuf = qbuf + 2048 * 1024;                // 4096x1024
  ushort* vbuf = kbuf + 4096 * 1024;                // 4096x1024
  ushort* Qrb = vbuf + 4096 * 1024;                 // 2048x1024
  ushort* attn = Qrb + 2048 * 1024;                 // 2048x1024

  concat_cvt_kernel<<<2048, 256, 0, stream>>>(x, mem, xt, xb);
  cvt_kernel<<<1024, 256, 0, stream>>>(rel, relb);
  transpose_cvt_kernel<<<dim3(32, 32), 256, 0, stream>>>(Wq, WqT);
  transpose_cvt_kernel<<<dim3(32, 32), 256, 0, stream>>>(Wke, WkeT);
  transpose_cvt_kernel<<<dim3(32, 32), 256, 0, stream>>>(Wkr, WkrT);
  transpose_cvt_kernel<<<dim3(32, 32), 256, 0, stream>>>(Wv, WvT);
  transpose_cvt_kernel<<<dim3(32, 32), 256, 0, stream>>>(Wo, WoT);

  gemm_bt_kernel<false><<<dim3(32, 16), 256, 0, stream>>>(xb, WqT, bq, qbuf, 2048, 1024, 1024);
  gemm_bt_kernel<false><<<dim3(64, 16), 256, 0, stream>>>(xt, WkeT, bke, kbuf, 4096, 1024, 1024);
  gemm_bt_kernel<false><<<dim3(64, 16), 256, 0, stream>>>(xt, WvT, bv, vbuf, 4096, 1024, 1024);
  gemm_bt_kernel<false><<<dim3(32, 16), 256, 0, stream>>>(relb, WkrT, bkr, Qrb, 2048, 1024, 1024);

  attn_mfma_kernel<<<dim3(SEQ / ST, NH, BATCH), 256, 0, stream>>>(
      qbuf, kbuf, vbuf, Qrb, mask, attn);

  gemm_bt_kernel<true><<<dim3(32, 16), 256, 0, stream>>>(attn, WoT, bo, out, 2048, 1024, 1024);
}

// Round 5
// 409.929 us; speedup vs baseline: 3.1039x; 1.2084x over previous
//
#include <hip/hip_runtime.h>

typedef unsigned short ushort;
typedef unsigned int uint;
typedef __attribute__((ext_vector_type(8))) short short8;
typedef __attribute__((ext_vector_type(4))) float float4v;

#define D_MODEL 1024
#define NH 16
#define DH 64
#define BATCH 2
#define SEQ 1024
#define MEMLEN 1024
#define TOT 2048

__device__ __forceinline__ float b2f(ushort u) {
  return __uint_as_float(((uint)u) << 16);
}
__device__ __forceinline__ ushort f2b(float f) {
  uint i = __float_as_uint(f);
  uint r = (i + 0x7fffu + ((i >> 16) & 1u)) >> 16;
  return (ushort)r;
}
// async global->LDS, 16B per lane; LDS dest = wave-uniform base + lane*16
__device__ __forceinline__ void gld16(const ushort* g, ushort* l) {
  __builtin_amdgcn_global_load_lds(
      (const __attribute__((address_space(1))) void*)g,
      (__attribute__((address_space(3))) void*)l, 16, 0, 0);
}

// ------------------------------------------------- concat + cast to bf16 ----
__global__ __launch_bounds__(256) void concat_cvt_kernel(
    const float* __restrict__ x, const float* __restrict__ mem,
    ushort* __restrict__ xt, ushort* __restrict__ xb) {
  int idx = blockIdx.x * 256 + threadIdx.x;   // 8-elem units
  int row = idx >> 7;                         // 0..4095
  int c8 = (idx & 127) << 3;
  int b = row >> 11;
  int i = row & 2047;
  const float* src = (i < MEMLEN) ? &mem[((b << 10) + i) * D_MODEL]
                                  : &x[((b << 10) + (i - MEMLEN)) * D_MODEL];
  float4 f0 = *(const float4*)(&src[c8]);
  float4 f1 = *(const float4*)(&src[c8 + 4]);
  ushort u[8] = {f2b(f0.x), f2b(f0.y), f2b(f0.z), f2b(f0.w),
                 f2b(f1.x), f2b(f1.y), f2b(f1.z), f2b(f1.w)};
  *(uint4*)(&xt[row * D_MODEL + c8]) = *(const uint4*)u;
  if (i >= MEMLEN)
    *(uint4*)(&xb[((b << 10) + (i - MEMLEN)) * D_MODEL + c8]) = *(const uint4*)u;
}

// --------------------------------------------------- fp32 -> bf16 cast ------
__global__ __launch_bounds__(256) void cvt_kernel(const float* __restrict__ in,
                                                  ushort* __restrict__ out) {
  int idx = blockIdx.x * 256 + threadIdx.x;
  int base = idx << 3;
  float4 f0 = *(const float4*)(&in[base]);
  float4 f1 = *(const float4*)(&in[base + 4]);
  ushort u[8] = {f2b(f0.x), f2b(f0.y), f2b(f0.z), f2b(f0.w),
                 f2b(f1.x), f2b(f1.y), f2b(f1.z), f2b(f1.w)};
  *(uint4*)(&out[base]) = *(const uint4*)u;
}

// --------------------------- 5x transpose + cast to bf16 (one launch) -------
__global__ __launch_bounds__(256) void transpose_cvt5_kernel(
    const float* __restrict__ W0, const float* __restrict__ W1,
    const float* __restrict__ W2, const float* __restrict__ W3,
    const float* __restrict__ W4, ushort* __restrict__ T0,
    ushort* __restrict__ T1, ushort* __restrict__ T2, ushort* __restrict__ T3,
    ushort* __restrict__ T4) {
  __shared__ ushort tle[32][33];
  const float* W;
  ushort* T;
  switch (blockIdx.z) {
    case 0: W = W0; T = T0; break;
    case 1: W = W1; T = T1; break;
    case 2: W = W2; T = T2; break;
    case 3: W = W3; T = T3; break;
    default: W = W4; T = T4; break;
  }
  const int bx = blockIdx.x * 32, by = blockIdx.y * 32;
  const int tx = threadIdx.x & 31, ty = threadIdx.x >> 5;
#pragma unroll
  for (int j = 0; j < 32; j += 8)
    tle[ty + j][tx] = f2b(W[(by + ty + j) * 1024 + bx + tx]);
  __syncthreads();
#pragma unroll
  for (int j = 0; j < 32; j += 8)
    T[(bx + ty + j) * 1024 + by + tx] = tle[tx][ty + j];
}

// -------------------------------------------------- 128x128 m97-style GEMM --
// C[M x N] = A[M x K] @ BT[N x K]^T + bias. BK=32, global_load_lds(16B).
// EPI 0: bf16 C row-major; 1: fp32 C row-major; 2: bf16 V^T per (b,head):
//   vt[((b*1024)+col)*2048 + t]  with row m = b*2048 + t.
template <int EPI>
__global__ __launch_bounds__(256) void gemm128_kernel(
    const ushort* __restrict__ A, const ushort* __restrict__ BT,
    const float* __restrict__ bias, void* __restrict__ Cout,
    int M, int N, int K) {
  __shared__ ushort As[128 * 32];
  __shared__ ushort Bs[128 * 32];
  const int m0 = blockIdx.x * 128, n0 = blockIdx.y * 128;
  const int tid = threadIdx.x;
  const int w = tid >> 6, lane = tid & 63, m15 = lane & 15, q4 = lane >> 4;
  const int wm = w & 1, wn = w >> 1;
  float4v acc[4][4] = {};

  const int c0 = tid, c1 = tid + 256;   // 16B staging units
  const int r0 = c0 >> 2, u0 = (c0 & 3) * 8;
  const int r1 = c1 >> 2, u1 = (c1 & 3) * 8;

  for (int kk = 0; kk < K; kk += 32) {
    __syncthreads();
    gld16(&A[(m0 + r0) * K + kk + u0], &As[c0 * 8]);
    gld16(&A[(m0 + r1) * K + kk + u1], &As[c1 * 8]);
    gld16(&BT[(n0 + r0) * K + kk + u0], &Bs[c0 * 8]);
    gld16(&BT[(n0 + r1) * K + kk + u1], &Bs[c1 * 8]);
    __syncthreads();
    short8 af[4], bf[4];
#pragma unroll
    for (int i = 0; i < 4; ++i)
      af[i] = *(const short8*)(&As[(wm * 64 + i * 16 + m15) * 32 + q4 * 8]);
#pragma unroll
    for (int j = 0; j < 4; ++j)
      bf[j] = *(const short8*)(&Bs[(wn * 64 + j * 16 + m15) * 32 + q4 * 8]);
#pragma unroll
    for (int i = 0; i < 4; ++i)
#pragma unroll
      for (int j = 0; j < 4; ++j)
        acc[i][j] =
            __builtin_amdgcn_mfma_f32_16x16x32_bf16(af[i], bf[j], acc[i][j], 0, 0, 0);
  }
#pragma unroll
  for (int j = 0; j < 4; ++j) {
    int col = n0 + wn * 64 + j * 16 + m15;
    float bv = bias[col];
#pragma unroll
    for (int i = 0; i < 4; ++i) {
      int rowb = m0 + wm * 64 + i * 16 + q4 * 4;
      if (EPI == 2) {
        ushort pk[4];
#pragma unroll
        for (int r = 0; r < 4; ++r) pk[r] = f2b(acc[i][j][r] + bv);
        int bb = rowb >> 11, t = rowb & 2047;
        *(uint2*)(&((ushort*)Cout)[(((bb << 10) + col) << 11) + t]) =
            *(const uint2*)pk;
      } else {
#pragma unroll
        for (int r = 0; r < 4; ++r) {
          float v = acc[i][j][r] + bv;
          if (EPI == 1)
            ((float*)Cout)[(rowb + r) * N + col] = v;
          else
            ((ushort*)Cout)[(rowb + r) * N + col] = f2b(v);
        }
      }
    }
  }
}

// ------------------------------------------- fused MFMA flash attention -----
// Block: 32 q-rows of one (b,h), 4 waves, t-chunks of 64, register-prefetch
// software pipeline (staging for chunk i+1 loaded to VGPRs during chunk i).
// u = t-s+1023. Main: q[s].Qrel[u] (u<=2047); wrap: q[s+1].Qrel[u-2049]
// (u>=2049); u==2048 -> 0 (zero-filled Btile cells).
// NOTE: Btile scatter MUST be += . Main and wrap passes write the SAME cells
// (each contributes 0 where its window rows were zero-staged); '=' lets the
// wrap pass clobber main's value with 0 in boundary chunks (R4 bug, 3.7e-3).
#define ST 32
#define TC 64
#define LQ 72     // ushort stride (144 B rows)
#define BW 96     // staged window rows

__global__ __launch_bounds__(256, 2) void attn_mfma_kernel(
    const ushort* __restrict__ qb, const ushort* __restrict__ kb,
    const ushort* __restrict__ vt, const ushort* __restrict__ Qr,
    const float* __restrict__ mask, ushort* __restrict__ attn) {
  __shared__ ushort qA[ST + 1][LQ];   // q rows s0..s0+32
  __shared__ ushort Kc[TC][LQ];       // K chunk [t][dh]
  __shared__ ushort Vt[DH][LQ];       // V chunk [dh][t]  (transposed!)
  __shared__ ushort Wm[BW][LQ];       // Qrel main window
  __shared__ ushort Ww[BW][LQ];       // Qrel wrap window
  __shared__ float Btile[ST][66];     // B-term (s x t) fp32
  __shared__ ushort Pt[ST][LQ];       // exp(scores) bf16
  __shared__ float red[ST][8];
  __shared__ float lsum[ST];

  const int s0 = blockIdx.x * ST;
  const int h = blockIdx.y;
  const int b = blockIdx.z;
  const int tid = threadIdx.x;
  const int w = tid >> 6, lane = tid & 63, m15 = lane & 15, q4 = lane >> 4;
  const int r8 = tid >> 3, c8 = (tid & 7) * 8;   // staging coords

  for (int idx = tid; idx < (ST + 1) * 8; idx += 256) {
    int r = idx >> 3, cc = (idx & 7) * 8;
    int srow = s0 + r;
    uint4 v = make_uint4(0u, 0u, 0u, 0u);
    if (srow < SEQ)
      v = *(const uint4*)(&qb[((b << 10) + srow) * D_MODEL + (h << 6) + cc]);
    *(uint4*)(&qA[r][cc]) = v;
  }
  if (tid < ST) lsum[tid] = 0.f;

  uint4 pk0, pk1, pv0, pv1, pm0, pm1, pm2, pw0, pw1, pw2;
  const uint4 z4 = make_uint4(0u, 0u, 0u, 0u);
  auto prefetch = [&](int t0n) {
    pk0 = pk1 = pv0 = pv1 = z4;
    pm0 = pm1 = pm2 = pw0 = pw1 = pw2 = z4;
    if (t0n < TOT) {
      const int umn = t0n - s0 + (SEQ - 1) - (ST - 1);
      pk0 = *(const uint4*)(&kb[((b << 11) + t0n + r8) * D_MODEL + (h << 6) + c8]);
      pk1 = *(const uint4*)(&kb[((b << 11) + t0n + r8 + 32) * D_MODEL + (h << 6) + c8]);
      pv0 = *(const uint4*)(&vt[(((b << 10) + (h << 6) + r8) << 11) + t0n + c8]);
      pv1 = *(const uint4*)(&vt[(((b << 10) + (h << 6) + r8 + 32) << 11) + t0n + c8]);
      if (umn <= TOT - 1) {   // main window needed
        int u0 = umn + r8, u1 = u0 + 32, u2 = u0 + 64;
        if (u0 < TOT) pm0 = *(const uint4*)(&Qr[u0 * D_MODEL + (h << 6) + c8]);
        if (u1 < TOT) pm1 = *(const uint4*)(&Qr[u1 * D_MODEL + (h << 6) + c8]);
        if (u2 < TOT) pm2 = *(const uint4*)(&Qr[u2 * D_MODEL + (h << 6) + c8]);
      }
      if (umn + (BW - 2) >= TOT + 1) {   // wrap window needed
        int j0 = umn - (TOT + 1) + r8, j1 = j0 + 32, j2 = j0 + 64;
        if (j0 >= 0) pw0 = *(const uint4*)(&Qr[j0 * D_MODEL + (h << 6) + c8]);
        if (j1 >= 0) pw1 = *(const uint4*)(&Qr[j1 * D_MODEL + (h << 6) + c8]);
        if (j2 >= 0) pw2 = *(const uint4*)(&Qr[j2 * D_MODEL + (h << 6) + c8]);
      }
    }
  };

  float4v oacc0 = {0.f, 0.f, 0.f, 0.f};
  float4v oacc1 = oacc0;
  prefetch(0);

  for (int t0 = 0; t0 < TOT; t0 += TC) {
    // mask preload for this chunk (global; hidden under the barrier)
    const int tcol = t0 + w * 16 + m15;
    float mreg[8];
#pragma unroll
    for (int mh = 0; mh < 2; ++mh)
#pragma unroll
      for (int i = 0; i < 4; ++i)
        mreg[mh * 4 + i] = mask[(s0 + mh * 16 + q4 * 4 + i) * TOT + tcol];

    __syncthreads();   // (A) prev chunk's LDS reads done
    if (t0 > 0 && tid < ST) {
      float ss = 0.f;
#pragma unroll
      for (int j = 0; j < 8; ++j) ss += red[tid][j];
      lsum[tid] += ss;
    }
    // store prefetched regs -> LDS
    *(uint4*)(&Kc[r8][c8]) = pk0;
    *(uint4*)(&Kc[r8 + 32][c8]) = pk1;
    *(uint4*)(&Vt[r8][c8]) = pv0;
    *(uint4*)(&Vt[r8 + 32][c8]) = pv1;
    *(uint4*)(&Wm[r8][c8]) = pm0;
    *(uint4*)(&Wm[r8 + 32][c8]) = pm1;
    *(uint4*)(&Wm[r8 + 64][c8]) = pm2;
    *(uint4*)(&Ww[r8][c8]) = pw0;
    *(uint4*)(&Ww[r8 + 32][c8]) = pw1;
    *(uint4*)(&Ww[r8 + 64][c8]) = pw2;
    for (int idx = tid; idx < ST * 66; idx += 256) ((float*)Btile)[idx] = 0.f;

    const int umin = t0 - s0 + (SEQ - 1) - (ST - 1);
    const bool mainC = (umin <= TOT - 1);
    const bool wrapC = (umin + (BW - 2) >= TOT + 1);
    __syncthreads();   // (B) staging visible
    prefetch(t0 + TC);   // issue next chunk's global loads (latency hidden)

    // ---- B-term GEMMs (32 x 96), diagonal scatter into Btile (+=!) ----
    if (mainC) {
#pragma unroll
      for (int j3 = 0; j3 < 3; ++j3) {
        int idx3 = w * 3 + j3, mh = idx3 & 1, nt = idx3 >> 1;
        float4v c = {0.f, 0.f, 0.f, 0.f};
#pragma unroll
        for (int ks = 0; ks < 2; ++ks) {
          short8 af = *(const short8*)(&qA[mh * 16 + m15][ks * 32 + q4 * 8]);
          short8 bf = *(const short8*)(&Wm[nt * 16 + m15][ks * 32 + q4 * 8]);
          c = __builtin_amdgcn_mfma_f32_16x16x32_bf16(af, bf, c, 0, 0, 0);
        }
        int slb = mh * 16 + q4 * 4, m = nt * 16 + m15;
#pragma unroll
        for (int i = 0; i < 4; ++i) {
          int tl = m + slb + i - (ST - 1);
          if ((unsigned)tl < TC) Btile[slb + i][tl] += c[i];
        }
      }
    }
    if (wrapC) {
#pragma unroll
      for (int j3 = 0; j3 < 3; ++j3) {
        int idx3 = w * 3 + j3, mh = idx3 & 1, nt = idx3 >> 1;
        float4v c = {0.f, 0.f, 0.f, 0.f};
#pragma unroll
        for (int ks = 0; ks < 2; ++ks) {
          short8 af = *(const short8*)(&qA[mh * 16 + m15 + 1][ks * 32 + q4 * 8]);
          short8 bf = *(const short8*)(&Ww[nt * 16 + m15][ks * 32 + q4 * 8]);
          c = __builtin_amdgcn_mfma_f32_16x16x32_bf16(af, bf, c, 0, 0, 0);
        }
        int slb = mh * 16 + q4 * 4, m = nt * 16 + m15;
#pragma unroll
        for (int i = 0; i < 4; ++i) {
          int tl = m + slb + i - (ST - 1);
          if ((unsigned)tl < TC) Btile[slb + i][tl] += c[i];
        }
      }
    }
    // ---- A-term GEMM: wave w owns t-cols w*16..w*16+15 ----
    float4v aA0 = {0.f, 0.f, 0.f, 0.f};
    float4v aA1 = aA0;
#pragma unroll
    for (int ks = 0; ks < 2; ++ks) {
      short8 bf = *(const short8*)(&Kc[w * 16 + m15][ks * 32 + q4 * 8]);
      short8 a0 = *(const short8*)(&qA[m15][ks * 32 + q4 * 8]);
      short8 a1 = *(const short8*)(&qA[16 + m15][ks * 32 + q4 * 8]);
      aA0 = __builtin_amdgcn_mfma_f32_16x16x32_bf16(a0, bf, aA0, 0, 0, 0);
      aA1 = __builtin_amdgcn_mfma_f32_16x16x32_bf16(a1, bf, aA1, 0, 0, 0);
    }
    __syncthreads();   // (C) Btile scatter complete

    // ---- scores -> exp -> Pt ----
    {
      int tl = w * 16 + m15;
#pragma unroll
      for (int mh = 0; mh < 2; ++mh) {
        float4v aa = mh ? aA1 : aA0;
#pragma unroll
        for (int i = 0; i < 4; ++i) {
          int sl = mh * 16 + q4 * 4 + i;
          float val = (aa[i] + Btile[sl][tl]) * 0.125f + mreg[mh * 4 + i] * -1e9f;
          Pt[sl][tl] = f2b(__expf(val));
        }
      }
    }
    __syncthreads();   // (D) Pt complete

    // partial row sums (vectorized read)
    {
      int row = tid >> 3, cb = (tid & 7) * 8;
      short8 p8 = *(const short8*)(&Pt[row][cb]);
      float ss = 0.f;
#pragma unroll
      for (int j = 0; j < 8; ++j) ss += b2f((ushort)p8[j]);
      red[row][tid & 7] = ss;
    }
    // ---- PV MFMA: wave w owns dh-cols w*16..w*16+15 ----
#pragma unroll
    for (int ks = 0; ks < 2; ++ks) {
      short8 vf = *(const short8*)(&Vt[w * 16 + m15][ks * 32 + q4 * 8]);
      short8 p0 = *(const short8*)(&Pt[m15][ks * 32 + q4 * 8]);
      short8 p1 = *(const short8*)(&Pt[16 + m15][ks * 32 + q4 * 8]);
      oacc0 = __builtin_amdgcn_mfma_f32_16x16x32_bf16(p0, vf, oacc0, 0, 0, 0);
      oacc1 = __builtin_amdgcn_mfma_f32_16x16x32_bf16(p1, vf, oacc1, 0, 0, 0);
    }
  }
  __syncthreads();
  if (tid < ST) {
    float ss = 0.f;
#pragma unroll
    for (int j = 0; j < 8; ++j) ss += red[tid][j];
    lsum[tid] += ss;
  }
  __syncthreads();
#pragma unroll
  for (int mh = 0; mh < 2; ++mh) {
    float4v acc = mh ? oacc1 : oacc0;
#pragma unroll
    for (int i = 0; i < 4; ++i) {
      int sl = mh * 16 + q4 * 4 + i;
      attn[((b << 10) + s0 + sl) * D_MODEL + (h << 6) + w * 16 + m15] =
          f2b(acc[i] / lsum[sl]);
    }
  }
}

// ---------------------------------------------------------------- launch ----
extern "C" void kernel_launch(void* const* d_in, const int* in_sizes, int n_in,
                              void* d_out, int out_size, void* d_ws,
                              size_t ws_size, hipStream_t stream) {
  const float* x = (const float*)d_in[0];
  const float* mem = (const float*)d_in[1];
  const float* mask = (const float*)d_in[2];
  const float* rel = (const float*)d_in[3];
  const float* Wq = (const float*)d_in[4];
  const float* bq = (const float*)d_in[5];
  const float* Wke = (const float*)d_in[6];
  const float* bke = (const float*)d_in[7];
  const float* Wkr = (const float*)d_in[8];
  const float* bkr = (const float*)d_in[9];
  const float* Wv = (const float*)d_in[10];
  const float* bv = (const float*)d_in[11];
  const float* Wo = (const float*)d_in[12];
  const float* bo = (const float*)d_in[13];
  float* out = (float*)d_out;

  char* ws = (char*)d_ws;
  ushort* xt = (ushort*)ws;                         // 4096x1024 bf16
  ushort* xb = xt + 4096 * 1024;                    // 2048x1024
  ushort* relb = xb + 2048 * 1024;                  // 2048x1024
  ushort* WqT = relb + 2048 * 1024;                 // 5 x 1024x1024
  ushort* WkeT = WqT + 1024 * 1024;
  ushort* WkrT = WkeT + 1024 * 1024;
  ushort* WvT = WkrT + 1024 * 1024;
  ushort* WoT = WvT + 1024 * 1024;
  ushort* qbuf = WoT + 1024 * 1024;                 // 2048x1024
  ushort* kbuf = qbuf + 2048 * 1024;                // 4096x1024
  ushort* vtb = kbuf + 4096 * 1024;                 // [b][h][dh][tot] 2Mx2B x2
  ushort* Qrb = vtb + 4096 * 1024;                  // 2048x1024
  ushort* attn = Qrb + 2048 * 1024;                 // 2048x1024

  concat_cvt_kernel<<<2048, 256, 0, stream>>>(x, mem, xt, xb);
  cvt_kernel<<<1024, 256, 0, stream>>>(rel, relb);
  transpose_cvt5_kernel<<<dim3(32, 32, 5), 256, 0, stream>>>(
      Wq, Wke, Wkr, Wv, Wo, WqT, WkeT, WkrT, WvT, WoT);

  gemm128_kernel<0><<<dim3(16, 8), 256, 0, stream>>>(xb, WqT, bq, qbuf, 2048, 1024, 1024);
  gemm128_kernel<0><<<dim3(32, 8), 256, 0, stream>>>(xt, WkeT, bke, kbuf, 4096, 1024, 1024);
  gemm128_kernel<2><<<dim3(32, 8), 256, 0, stream>>>(xt, WvT, bv, vtb, 4096, 1024, 1024);
  gemm128_kernel<0><<<dim3(16, 8), 256, 0, stream>>>(relb, WkrT, bkr, Qrb, 2048, 1024, 1024);

  attn_mfma_kernel<<<dim3(SEQ / ST, NH, BATCH), 256, 0, stream>>>(
      qbuf, kbuf, vtb, Qrb, mask, attn);

  gemm128_kernel<1><<<dim3(16, 8), 256, 0, stream>>>(attn, WoT, bo, out, 2048, 1024, 1024);
}